// Round 5
// baseline (386.902 us; speedup 1.0000x reference)
//
#include <hip/hip_runtime.h>
#include <hip/hip_bf16.h>
#include <cstdint>

#define GLOBAL_AS __attribute__((address_space(1)))
#define LDS_AS    __attribute__((address_space(3)))

typedef short s8v  __attribute__((ext_vector_type(8)));
typedef float f4v  __attribute__((ext_vector_type(4)));
typedef unsigned short u8s __attribute__((ext_vector_type(8)));

#define NEGV (-1e7f)

__device__ __forceinline__ void gload_lds16(const void* g, void* l) {
  __builtin_amdgcn_global_load_lds((const GLOBAL_AS uint32_t*)g,
                                   (LDS_AS uint32_t*)l, 16, 0, 0);
}

__device__ __forceinline__ unsigned short f2bf(float f) {
  union { float f; uint32_t u; } v; v.f = f;
  uint32_t u = v.u;
  u += 0x7fffu + ((u >> 16) & 1u);
  return (unsigned short)(u >> 16);
}

// ---------------- convert bert_out (f32) -> bf16, same layout ----------------
__global__ __launch_bounds__(256) void cvt_a(const float* __restrict__ x,
                                             unsigned short* __restrict__ y,
                                             int n8) {
  int i = blockIdx.x * blockDim.x + threadIdx.x;
  int stride = gridDim.x * blockDim.x;
  for (; i < n8; i += stride) {
    float4 a = ((const float4*)x)[2 * i + 0];
    float4 b = ((const float4*)x)[2 * i + 1];
    u8s o;
    o[0] = f2bf(a.x); o[1] = f2bf(a.y); o[2] = f2bf(a.z); o[3] = f2bf(a.w);
    o[4] = f2bf(b.x); o[5] = f2bf(b.y); o[6] = f2bf(b.z); o[7] = f2bf(b.w);
    ((u8s*)y)[i] = o;
  }
}

// ------------- convert + transpose W1 (K x N f32) -> W1T (N x K bf16) -------------
__global__ __launch_bounds__(256) void cvt_w1t(const float* __restrict__ w1,
                                               unsigned short* __restrict__ w1t) {
  __shared__ float tile[32][33];
  int bx = blockIdx.x & 31;   // n-tile
  int by = blockIdx.x >> 5;   // k-tile
  int tx = threadIdx.x & 31;
  int ty = threadIdx.x >> 5;  // 0..7
#pragma unroll
  for (int j = 0; j < 4; ++j) {
    int kk = ty + j * 8;
    tile[kk][tx] = w1[(size_t)(by * 32 + kk) * 1024 + bx * 32 + tx];
  }
  __syncthreads();
#pragma unroll
  for (int j = 0; j < 4; ++j) {
    int nn = ty + j * 8;
    w1t[(size_t)(bx * 32 + nn) * 1024 + by * 32 + tx] = f2bf(tile[tx][nn]);
  }
}

// ---------------- ABLATION GEMM family (within-probe A/B, rule #13) ----------------
// MODE 0: control = R4 8-phase full pipeline (swizzled source + swizzled reads). REAL output.
// MODE 1: full pipeline, LINEAR global source + XOR reads (garbage data, dummy out):
//         same LDS/bank/instruction mix as MODE 0; only global addr pattern differs -> TA test.
// MODE 2: no global in loop: tile0 staged once; pure ds_read+MFMA+barrier phases (dummy out).
// MODE 3: no global, no LDS in loop: pure MFMA+barrier convoy (frags one-time loaded, dummy out).
template <int MODE>
__global__ __launch_bounds__(512, 2) void gemm_v(
    const unsigned short* __restrict__ Abf,   // [16384][1024] bf16
    const unsigned short* __restrict__ Bbf,   // [1024][1024] bf16 (W1^T)
    const float* __restrict__ b1,
    const float* __restrict__ W2,             // [1024][3] f32
    float* __restrict__ logits)               // [16384][3] f32, pre-zeroed
{
  __shared__ __align__(16) char lds[147456];  // 2x64KB tile bufs + 16KB dummy

  int bid = blockIdx.x;
  int wid = (bid & 7) * 32 + (bid >> 3);
  int mt = wid >> 2;   // 0..63
  int nt = wid & 3;    // 0..3

  int tid  = threadIdx.x;
  int lane = tid & 63;
  int wv   = tid >> 6;  // 0..7
  int wr   = wv >> 2;   // wave row (0..1)
  int wc   = wv & 3;    // wave col (0..3)

  int laneq = lane & 15;
  int klo   = (lane >> 4) << 4;
  int sw    = (laneq & 7) << 4;
  int x0    = klo ^ sw;           // XOR'd read offsets (MODE 0,1,2)
  int x1    = (64 + klo) ^ sw;

  const size_t arow0 = (size_t)mt * 256;
  const size_t brow0 = (size_t)nt * 256;

  // staging source col: MODE 0,2 pre-swizzled; MODE 1 linear (TA test)
  int scol = (MODE == 1) ? ((lane & 7) * 16)
                         : (((lane & 7) * 16) ^ ((lane >> 3) << 4));
  const unsigned short* gA = Abf + (arow0 + (lane >> 3)) * 1024 + (scol >> 1)
                                 + (size_t)wv * 16 * 1024;
  const unsigned short* gB = Bbf + (brow0 + (lane >> 3)) * 1024 + (scol >> 1)
                                 + (size_t)wv * 16 * 1024;

  f4v acc[8][4];
#pragma unroll
  for (int m = 0; m < 8; ++m)
#pragma unroll
    for (int n = 0; n < 4; ++n)
      acc[m][n] = f4v{0.f, 0.f, 0.f, 0.f};

  s8v a_frag[4][2];
  s8v b_frag[2][2][2];

  auto STAGE = [&](int ts, int isB, int rh) {
    int ok  = ts < 16;
    int tcl = ok ? ts : 15;
    const unsigned short* g = (isB ? gB : gA) + (size_t)rh * 128 * 1024 + tcl * 64;
    int dst = ok ? (((tcl & 1) << 16) | (isB << 15) | (rh << 14) | (wv << 11))
                 : (131072 + (wv << 11));
    gload_lds16(g,            lds + dst);
    gload_lds16(g + 8 * 1024, lds + dst + 1024);
  };

  auto READ_A = [&](int buf, int mq) {
    const char* p = lds + (buf << 16) + (wr << 14) + laneq * 128 + mq * 8192;
#pragma unroll
    for (int m = 0; m < 4; ++m) {
      a_frag[m][0] = *(const s8v*)(p + m * 2048 + x0);
      a_frag[m][1] = *(const s8v*)(p + m * 2048 + x1);
    }
  };
  auto READ_B = [&](int buf, int np) {
    const char* p = lds + (buf << 16) + 32768 + ((wc >> 1) << 14)
                        + ((wc & 1) * 64 + laneq) * 128 + np * 4096;
#pragma unroll
    for (int n2 = 0; n2 < 2; ++n2) {
      b_frag[np][n2][0] = *(const s8v*)(p + n2 * 2048 + x0);
      b_frag[np][n2][1] = *(const s8v*)(p + n2 * 2048 + x1);
    }
  };
  auto MFMA_Q = [&](int mq, int np) {
    __builtin_amdgcn_s_setprio(1);
#pragma unroll
    for (int m = 0; m < 4; ++m)
#pragma unroll
      for (int n2 = 0; n2 < 2; ++n2) {
        acc[mq*4+m][np*2+n2] = __builtin_amdgcn_mfma_f32_16x16x32_bf16(
            a_frag[m][0], b_frag[np][n2][0], acc[mq*4+m][np*2+n2], 0, 0, 0);
        acc[mq*4+m][np*2+n2] = __builtin_amdgcn_mfma_f32_16x16x32_bf16(
            a_frag[m][1], b_frag[np][n2][1], acc[mq*4+m][np*2+n2], 0, 0, 0);
      }
    __builtin_amdgcn_s_setprio(0);
  };

#define BAR  __builtin_amdgcn_s_barrier()
#define SB0  __builtin_amdgcn_sched_barrier(0)
#define VM4  asm volatile("s_waitcnt vmcnt(4)" ::: "memory")
#define VM0  asm volatile("s_waitcnt vmcnt(0)" ::: "memory")

  if constexpr (MODE <= 1) {
    // prologue: tile0 all 4 slots + tile1 {B,h0},{A,h0}
    STAGE(0,1,0); STAGE(0,0,0); STAGE(0,0,1); STAGE(0,1,1);
    STAGE(1,1,0); STAGE(1,0,0);
    VM4; BAR;
    for (int i = 0; i < 8; ++i) {
      int T = 2 * i;
      READ_A(0,0); READ_B(0,0); STAGE(T+1,0,1);
      BAR; SB0; MFMA_Q(0,0); SB0; BAR;
      READ_B(0,1);             STAGE(T+1,1,1);
      BAR; SB0; MFMA_Q(0,1); SB0; BAR;
      READ_A(0,1);             STAGE(T+2,1,0);
      BAR; SB0; MFMA_Q(1,1); SB0; BAR;
                               STAGE(T+2,0,0);
      VM4;
      BAR; SB0; MFMA_Q(1,0); SB0; BAR;
      READ_A(1,0); READ_B(1,0); STAGE(T+2,0,1);
      BAR; SB0; MFMA_Q(0,0); SB0; BAR;
      READ_B(1,1);             STAGE(T+2,1,1);
      BAR; SB0; MFMA_Q(0,1); SB0; BAR;
      READ_A(1,1);             STAGE(T+3,1,0);
      BAR; SB0; MFMA_Q(1,1); SB0; BAR;
                               STAGE(T+3,0,0);
      VM4;
      BAR; SB0; MFMA_Q(1,0); SB0; BAR;
    }
  } else if constexpr (MODE == 2) {
    // stage tile 0 once; loop has NO global ops
    STAGE(0,1,0); STAGE(0,0,0); STAGE(0,0,1); STAGE(0,1,1);
    VM0; BAR;
    for (int i = 0; i < 8; ++i) {
      for (int h = 0; h < 2; ++h) {
        READ_A(0,0); READ_B(0,0);
        BAR; SB0; MFMA_Q(0,0); SB0; BAR;
        READ_B(0,1);
        BAR; SB0; MFMA_Q(0,1); SB0; BAR;
        READ_A(0,1);
        BAR; SB0; MFMA_Q(1,1); SB0; BAR;
        BAR; SB0; MFMA_Q(1,0); SB0; BAR;
      }
    }
  } else {
    // MODE 3: one-time frag load (real data, defeats CSE), then pure MFMA+barrier convoy
#pragma unroll
    for (int m = 0; m < 4; ++m) {
      a_frag[m][0] = *(const s8v*)(Abf + (size_t)lane * 64 + m * 16);
      a_frag[m][1] = *(const s8v*)(Abf + (size_t)lane * 64 + m * 16 + 8);
    }
#pragma unroll
    for (int np = 0; np < 2; ++np)
#pragma unroll
      for (int n2 = 0; n2 < 2; ++n2) {
        b_frag[np][n2][0] = *(const s8v*)(Bbf + (size_t)lane * 64 + (np * 2 + n2) * 16);
        b_frag[np][n2][1] = *(const s8v*)(Bbf + (size_t)lane * 64 + (np * 2 + n2) * 16 + 8);
      }
    VM0; BAR;
    for (int i = 0; i < 8; ++i) {
      for (int h = 0; h < 2; ++h) {
        BAR; SB0; MFMA_Q(0,0); SB0; BAR;
        BAR; SB0; MFMA_Q(0,1); SB0; BAR;
        BAR; SB0; MFMA_Q(1,1); SB0; BAR;
        BAR; SB0; MFMA_Q(1,0); SB0; BAR;
      }
    }
  }

#undef BAR
#undef SB0
#undef VM4
#undef VM0

  // epilogue: h = relu(acc + b1); logits += h * W2 (shfl-reduce over 16 lanes)
  float b1v[4];
  float w2v[4][3];
#pragma unroll
  for (int n = 0; n < 4; ++n) {
    int gc = nt * 256 + wc * 64 + n * 16 + laneq;
    b1v[n] = b1[gc];
    w2v[n][0] = W2[gc * 3 + 0];
    w2v[n][1] = W2[gc * 3 + 1];
    w2v[n][2] = W2[gc * 3 + 2];
  }
#pragma unroll
  for (int m = 0; m < 8; ++m) {
#pragma unroll
    for (int q = 0; q < 4; ++q) {
      float p0 = 0.f, p1 = 0.f, p2 = 0.f;
#pragma unroll
      for (int n = 0; n < 4; ++n) {
        float h = acc[m][n][q] + b1v[n];
        h = fmaxf(h, 0.f);
        p0 += h * w2v[n][0];
        p1 += h * w2v[n][1];
        p2 += h * w2v[n][2];
      }
#pragma unroll
      for (int s = 1; s < 16; s <<= 1) {
        p0 += __shfl_xor(p0, s, 64);
        p1 += __shfl_xor(p1, s, 64);
        p2 += __shfl_xor(p2, s, 64);
      }
      if ((lane & 15) == 0) {
        int grow = mt * 256 + wr * 128 + m * 16 + (lane >> 4) * 4 + q;
        atomicAdd(&logits[grow * 3 + 0], p0);
        atomicAdd(&logits[grow * 3 + 1], p1);
        atomicAdd(&logits[grow * 3 + 2], p2);
      }
    }
  }
}

// ---------------- finalize: log-softmax, gather, logsumexp ----------------
__device__ __forceinline__ float blockReduceSum(float v, float* red, int t) {
#pragma unroll
  for (int s = 32; s >= 1; s >>= 1) v += __shfl_xor(v, s, 64);
  __syncthreads();
  if ((t & 63) == 0) red[t >> 6] = v;
  __syncthreads();
  return red[0] + red[1] + red[2] + red[3];
}

__global__ __launch_bounds__(256) void finalize(
    const float* __restrict__ logits,   // [16384][3]
    const float* __restrict__ b2,       // [3]
    const int* __restrict__ seq_mask,   // [32][512]
    const int* __restrict__ ans,        // [32][8][512]
    const int* __restrict__ span,       // [32][512]
    const int* __restrict__ isbio,      // [32]
    float* __restrict__ out)            // [32]
{
  int b = blockIdx.x;
  int t = threadIdx.x;
  __shared__ float lp[512][3];
  __shared__ float red[4];
  __shared__ float seq_ll[9];
  __shared__ int preg;

  float b20 = b2[0], b21 = b2[1], b22 = b2[2];

  for (int l = t; l < 512; l += 256) {
    int gi = b * 512 + l;
    float x0 = logits[gi * 3 + 0] + b20;
    float x1 = logits[gi * 3 + 1] + b21;
    float x2 = logits[gi * 3 + 2] + b22;
    float mx = fmaxf(x0, fmaxf(x1, x2));
    float lse = mx + logf(expf(x0 - mx) + expf(x1 - mx) + expf(x2 - mx));
    float msk = (float)seq_mask[gi];
    lp[l][0] = (x0 - lse) * msk;
    lp[l][1] = (x1 - lse) * msk;
    lp[l][2] = (x2 - lse) * msk;
  }
  __syncthreads();

  // is_pregen = sum(ans * seq_mask) > 0
  float s = 0.f;
  for (int i = t; i < 8 * 512; i += 256) {
    int m = i >> 9, l = i & 511;
    s += (float)(ans[(b * 8 + m) * 512 + l] * seq_mask[b * 512 + l]);
  }
  s = blockReduceSum(s, red, t);
  if (t == 0) preg = (s > 0.f) ? 1 : 0;
  __syncthreads();
  int ip = preg;

  for (int m = 0; m < 9; ++m) {
    float sll = 0.f, sidx = 0.f;
    for (int l = t; l < 512; l += 256) {
      int idx;
      if (m < 8) idx = ans[(b * 8 + m) * 512 + l] * seq_mask[b * 512 + l];
      else       idx = span[b * 512 + l] * (1 - ip);
      sll  += lp[l][idx];
      sidx += (float)idx;
    }
    sll  = blockReduceSum(sll, red, t);
    sidx = blockReduceSum(sidx, red, t);
    if (t == 0) seq_ll[m] = (sidx > 0.f) ? sll : NEGV;
  }

  if (t == 0) {
    float mx = seq_ll[0];
#pragma unroll
    for (int m = 1; m < 9; ++m) mx = fmaxf(mx, seq_ll[m]);
    float sum = 0.f;
#pragma unroll
    for (int m = 0; m < 9; ++m) sum += expf(seq_ll[m] - mx);
    float lml = mx + logf(sum);
    out[b] = isbio[b] ? lml : NEGV;
  }
}

extern "C" void kernel_launch(void* const* d_in, const int* in_sizes, int n_in,
                              void* d_out, int out_size, void* d_ws, size_t ws_size,
                              hipStream_t stream) {
  const float* bert     = (const float*)d_in[0];
  const int*   seq_mask = (const int*)d_in[1];
  const int*   ans      = (const int*)d_in[4];
  const int*   span     = (const int*)d_in[5];
  const int*   isbio    = (const int*)d_in[6];
  const float* W1       = (const float*)d_in[7];
  const float* b1       = (const float*)d_in[8];
  const float* W2       = (const float*)d_in[9];
  const float* b2       = (const float*)d_in[10];
  float* out = (float*)d_out;

  char* ws = (char*)d_ws;
  float* logits   = (float*)ws;                 // real (V0)     192 KB
  float* logits1  = (float*)(ws + 196608);      // V1 dummy      192 KB
  float* logits2  = (float*)(ws + 393216);      // V2 dummy      192 KB
  float* logits3  = (float*)(ws + 589824);      // V3 dummy      192 KB
  unsigned short* Abf = (unsigned short*)(ws + (1 << 20));                                // 32 MB
  unsigned short* W1T = (unsigned short*)(ws + (1 << 20) + (size_t)16384 * 1024 * 2);     // 2 MB

  hipMemsetAsync(logits, 0, 4 * 196608, stream);  // zero all four logit buffers
  cvt_a<<<2048, 256, 0, stream>>>(bert, Abf, 16384 * 1024 / 8);
  cvt_w1t<<<1024, 256, 0, stream>>>(W1, W1T);
  gemm_v<3><<<256, 512, 0, stream>>>(Abf, W1T, b1, W2, logits3);  // MFMA+barrier only
  gemm_v<2><<<256, 512, 0, stream>>>(Abf, W1T, b1, W2, logits2);  // +LDS reads
  gemm_v<1><<<256, 512, 0, stream>>>(Abf, W1T, b1, W2, logits1);  // full, linear source
  gemm_v<0><<<256, 512, 0, stream>>>(Abf, W1T, b1, W2, logits);   // control (REAL)
  finalize<<<32, 256, 0, stream>>>(logits, b2, seq_mask, ans, span, isbio, out);
}

// Round 6
// 78.103 us; speedup vs baseline: 4.9537x; 4.9537x over previous
//
#include <hip/hip_runtime.h>
#include <hip/hip_bf16.h>
#include <cstdint>

#define GLOBAL_AS __attribute__((address_space(1)))
#define LDS_AS    __attribute__((address_space(3)))

typedef short s8v  __attribute__((ext_vector_type(8)));
typedef float f4v  __attribute__((ext_vector_type(4)));
typedef unsigned short u8s __attribute__((ext_vector_type(8)));

#define NEGV (-1e7f)

__device__ __forceinline__ void gload_lds16(const void* g, void* l) {
  __builtin_amdgcn_global_load_lds((const GLOBAL_AS uint32_t*)g,
                                   (LDS_AS uint32_t*)l, 16, 0, 0);
}

__device__ __forceinline__ unsigned short f2bf(float f) {
  union { float f; uint32_t u; } v; v.f = f;
  uint32_t u = v.u;
  u += 0x7fffu + ((u >> 16) & 1u);
  return (unsigned short)(u >> 16);
}

// ---------------- convert bert_out (f32) -> bf16, same layout ----------------
__global__ __launch_bounds__(256) void cvt_a(const float* __restrict__ x,
                                             unsigned short* __restrict__ y,
                                             int n8) {
  int i = blockIdx.x * blockDim.x + threadIdx.x;
  int stride = gridDim.x * blockDim.x;
  for (; i < n8; i += stride) {
    float4 a = ((const float4*)x)[2 * i + 0];
    float4 b = ((const float4*)x)[2 * i + 1];
    u8s o;
    o[0] = f2bf(a.x); o[1] = f2bf(a.y); o[2] = f2bf(a.z); o[3] = f2bf(a.w);
    o[4] = f2bf(b.x); o[5] = f2bf(b.y); o[6] = f2bf(b.z); o[7] = f2bf(b.w);
    ((u8s*)y)[i] = o;
  }
}

// ------------- convert + transpose W1 (K x N f32) -> W1T (N x K bf16) -------------
__global__ __launch_bounds__(256) void cvt_w1t(const float* __restrict__ w1,
                                               unsigned short* __restrict__ w1t) {
  __shared__ float tile[32][33];
  int bx = blockIdx.x & 31;   // n-tile
  int by = blockIdx.x >> 5;   // k-tile
  int tx = threadIdx.x & 31;
  int ty = threadIdx.x >> 5;  // 0..7
#pragma unroll
  for (int j = 0; j < 4; ++j) {
    int kk = ty + j * 8;
    tile[kk][tx] = w1[(size_t)(by * 32 + kk) * 1024 + bx * 32 + tx];
  }
  __syncthreads();
#pragma unroll
  for (int j = 0; j < 4; ++j) {
    int nn = ty + j * 8;
    w1t[(size_t)(bx * 32 + nn) * 1024 + by * 32 + tx] = f2bf(tile[tx][nn]);
  }
}

// ---------------- fused GEMM: h = relu(A*W1 + b1); partial logits ----------------
// 256x256 tile, BK=64, 8 waves (2M x 4N), 8-phase counted-vmcnt schedule (R4,
// ledger-verified). EPILOGUE (R5 fix): NO atomics — R5 ablation showed the
// 196,608 atomicAdds were the ~80us wall (WRITE_SIZE 24576.0 KB == 196608 x
// 128B line RMWs exactly). Each block LDS-reduces its 4 wc-waves' partials and
// does ONE coalesced 3KB store into partials[nt][16384][3]; finalize sums 4.
__global__ __launch_bounds__(512, 2) void gemm_fused(
    const unsigned short* __restrict__ Abf,   // [16384][1024] bf16
    const unsigned short* __restrict__ Bbf,   // [1024][1024] bf16 (W1^T)
    const float* __restrict__ b1,
    const float* __restrict__ W2,             // [1024][3] f32
    float* __restrict__ partials)             // [4][16384][3] f32
{
  __shared__ __align__(16) char lds[147456];  // 2x64KB tile bufs + 16KB dummy

  // bijective XCD swizzle: 256 wgs, 8 XCDs, 32 per XCD
  int bid = blockIdx.x;
  int wid = (bid & 7) * 32 + (bid >> 3);
  int mt = wid >> 2;   // 0..63
  int nt = wid & 3;    // 0..3

  int tid  = threadIdx.x;
  int lane = tid & 63;
  int wv   = tid >> 6;  // 0..7
  int wr   = wv >> 2;   // wave row (0..1): rows wr*128..+127
  int wc   = wv & 3;    // wave col (0..3): cols wc*64..+63

  int laneq = lane & 15;
  int klo   = (lane >> 4) << 4;
  int sw    = (laneq & 7) << 4;
  int x0    = klo ^ sw;
  int x1    = (64 + klo) ^ sw;

  const size_t arow0 = (size_t)mt * 256;
  const size_t brow0 = (size_t)nt * 256;

  int scol = ((lane & 7) * 16) ^ ((lane >> 3) << 4);
  const unsigned short* gA = Abf + (arow0 + (lane >> 3)) * 1024 + (scol >> 1)
                                 + (size_t)wv * 16 * 1024;
  const unsigned short* gB = Bbf + (brow0 + (lane >> 3)) * 1024 + (scol >> 1)
                                 + (size_t)wv * 16 * 1024;

  f4v acc[8][4];
#pragma unroll
  for (int m = 0; m < 8; ++m)
#pragma unroll
    for (int n = 0; n < 4; ++n)
      acc[m][n] = f4v{0.f, 0.f, 0.f, 0.f};

  s8v a_frag[4][2];
  s8v b_frag[2][2][2];

  auto STAGE = [&](int ts, int isB, int rh) {
    int ok  = ts < 16;
    int tcl = ok ? ts : 15;
    const unsigned short* g = (isB ? gB : gA) + (size_t)rh * 128 * 1024 + tcl * 64;
    int dst = ok ? (((tcl & 1) << 16) | (isB << 15) | (rh << 14) | (wv << 11))
                 : (131072 + (wv << 11));
    gload_lds16(g,            lds + dst);
    gload_lds16(g + 8 * 1024, lds + dst + 1024);
  };

  auto READ_A = [&](int buf, int mq) {
    const char* p = lds + (buf << 16) + (wr << 14) + laneq * 128 + mq * 8192;
#pragma unroll
    for (int m = 0; m < 4; ++m) {
      a_frag[m][0] = *(const s8v*)(p + m * 2048 + x0);
      a_frag[m][1] = *(const s8v*)(p + m * 2048 + x1);
    }
  };
  auto READ_B = [&](int buf, int np) {
    const char* p = lds + (buf << 16) + 32768 + ((wc >> 1) << 14)
                        + ((wc & 1) * 64 + laneq) * 128 + np * 4096;
#pragma unroll
    for (int n2 = 0; n2 < 2; ++n2) {
      b_frag[np][n2][0] = *(const s8v*)(p + n2 * 2048 + x0);
      b_frag[np][n2][1] = *(const s8v*)(p + n2 * 2048 + x1);
    }
  };
  auto MFMA_Q = [&](int mq, int np) {
    __builtin_amdgcn_s_setprio(1);
#pragma unroll
    for (int m = 0; m < 4; ++m)
#pragma unroll
      for (int n2 = 0; n2 < 2; ++n2) {
        acc[mq*4+m][np*2+n2] = __builtin_amdgcn_mfma_f32_16x16x32_bf16(
            a_frag[m][0], b_frag[np][n2][0], acc[mq*4+m][np*2+n2], 0, 0, 0);
        acc[mq*4+m][np*2+n2] = __builtin_amdgcn_mfma_f32_16x16x32_bf16(
            a_frag[m][1], b_frag[np][n2][1], acc[mq*4+m][np*2+n2], 0, 0, 0);
      }
    __builtin_amdgcn_s_setprio(0);
  };

#define BAR  __builtin_amdgcn_s_barrier()
#define SB0  __builtin_amdgcn_sched_barrier(0)
#define VM4  asm volatile("s_waitcnt vmcnt(4)" ::: "memory")

  STAGE(0,1,0); STAGE(0,0,0); STAGE(0,0,1); STAGE(0,1,1);
  STAGE(1,1,0); STAGE(1,0,0);
  VM4; BAR;

  for (int i = 0; i < 8; ++i) {
    int T = 2 * i;
    READ_A(0,0); READ_B(0,0); STAGE(T+1,0,1);
    BAR; SB0; MFMA_Q(0,0); SB0; BAR;
    READ_B(0,1);             STAGE(T+1,1,1);
    BAR; SB0; MFMA_Q(0,1); SB0; BAR;
    READ_A(0,1);             STAGE(T+2,1,0);
    BAR; SB0; MFMA_Q(1,1); SB0; BAR;
                             STAGE(T+2,0,0);
    VM4;
    BAR; SB0; MFMA_Q(1,0); SB0; BAR;
    READ_A(1,0); READ_B(1,0); STAGE(T+2,0,1);
    BAR; SB0; MFMA_Q(0,0); SB0; BAR;
    READ_B(1,1);             STAGE(T+2,1,1);
    BAR; SB0; MFMA_Q(0,1); SB0; BAR;
    READ_A(1,1);             STAGE(T+3,1,0);
    BAR; SB0; MFMA_Q(1,1); SB0; BAR;
                             STAGE(T+3,0,0);
    VM4;
    BAR; SB0; MFMA_Q(1,0); SB0; BAR;
  }

#undef BAR
#undef SB0
#undef VM4

  // ---- epilogue: h = relu(acc + b1); p = h*W2; shfl-reduce; LDS-reduce over wc;
  //      ONE coalesced store per block (no atomics) ----
  float b1v[4];
  float w2v[4][3];
#pragma unroll
  for (int n = 0; n < 4; ++n) {
    int gc = nt * 256 + wc * 64 + n * 16 + laneq;
    b1v[n] = b1[gc];
    w2v[n][0] = W2[gc * 3 + 0];
    w2v[n][1] = W2[gc * 3 + 1];
    w2v[n][2] = W2[gc * 3 + 2];
  }

  float* red = (float*)lds;   // [4 wc][256 rows][3] f32 = 12 KB (K-loop LDS is dead)
#pragma unroll
  for (int m = 0; m < 8; ++m) {
#pragma unroll
    for (int q = 0; q < 4; ++q) {
      float p0 = 0.f, p1 = 0.f, p2 = 0.f;
#pragma unroll
      for (int n = 0; n < 4; ++n) {
        float h = acc[m][n][q] + b1v[n];
        h = fmaxf(h, 0.f);
        p0 += h * w2v[n][0];
        p1 += h * w2v[n][1];
        p2 += h * w2v[n][2];
      }
#pragma unroll
      for (int s = 1; s < 16; s <<= 1) {
        p0 += __shfl_xor(p0, s, 64);
        p1 += __shfl_xor(p1, s, 64);
        p2 += __shfl_xor(p2, s, 64);
      }
      if ((lane & 15) == 0) {
        int row = wr * 128 + m * 16 + (lane >> 4) * 4 + q;   // 0..255
        red[(wc * 256 + row) * 3 + 0] = p0;
        red[(wc * 256 + row) * 3 + 1] = p1;
        red[(wc * 256 + row) * 3 + 2] = p2;
      }
    }
  }
  __syncthreads();
  if (tid < 256) {
    float s0 = 0.f, s1 = 0.f, s2 = 0.f;
#pragma unroll
    for (int w = 0; w < 4; ++w) {
      s0 += red[(w * 256 + tid) * 3 + 0];
      s1 += red[(w * 256 + tid) * 3 + 1];
      s2 += red[(w * 256 + tid) * 3 + 2];
    }
    size_t o = ((size_t)nt * 16384 + (size_t)mt * 256 + tid) * 3;
    partials[o + 0] = s0;
    partials[o + 1] = s1;
    partials[o + 2] = s2;
  }
}

// ---------------- finalize: sum partials, log-softmax, gather, logsumexp ----------------
__device__ __forceinline__ float blockReduceSum(float v, float* red, int t) {
#pragma unroll
  for (int s = 32; s >= 1; s >>= 1) v += __shfl_xor(v, s, 64);
  __syncthreads();
  if ((t & 63) == 0) red[t >> 6] = v;
  __syncthreads();
  return red[0] + red[1] + red[2] + red[3];
}

__global__ __launch_bounds__(256) void finalize(
    const float* __restrict__ partials, // [4][16384][3]
    const float* __restrict__ b2,       // [3]
    const int* __restrict__ seq_mask,   // [32][512]
    const int* __restrict__ ans,        // [32][8][512]
    const int* __restrict__ span,       // [32][512]
    const int* __restrict__ isbio,      // [32]
    float* __restrict__ out)            // [32]
{
  int b = blockIdx.x;
  int t = threadIdx.x;
  __shared__ float lp[512][3];
  __shared__ float red[4];
  __shared__ float seq_ll[9];
  __shared__ int preg;

  float b20 = b2[0], b21 = b2[1], b22 = b2[2];
  const int NP = 16384 * 3;

  for (int l = t; l < 512; l += 256) {
    int gi = b * 512 + l;
    float x0 = b20, x1 = b21, x2 = b22;
#pragma unroll
    for (int w = 0; w < 4; ++w) {
      x0 += partials[w * NP + gi * 3 + 0];
      x1 += partials[w * NP + gi * 3 + 1];
      x2 += partials[w * NP + gi * 3 + 2];
    }
    float mx = fmaxf(x0, fmaxf(x1, x2));
    float lse = mx + logf(expf(x0 - mx) + expf(x1 - mx) + expf(x2 - mx));
    float msk = (float)seq_mask[gi];
    lp[l][0] = (x0 - lse) * msk;
    lp[l][1] = (x1 - lse) * msk;
    lp[l][2] = (x2 - lse) * msk;
  }
  __syncthreads();

  // is_pregen = sum(ans * seq_mask) > 0
  float s = 0.f;
  for (int i = t; i < 8 * 512; i += 256) {
    int m = i >> 9, l = i & 511;
    s += (float)(ans[(b * 8 + m) * 512 + l] * seq_mask[b * 512 + l]);
  }
  s = blockReduceSum(s, red, t);
  if (t == 0) preg = (s > 0.f) ? 1 : 0;
  __syncthreads();
  int ip = preg;

  for (int m = 0; m < 9; ++m) {
    float sll = 0.f, sidx = 0.f;
    for (int l = t; l < 512; l += 256) {
      int idx;
      if (m < 8) idx = ans[(b * 8 + m) * 512 + l] * seq_mask[b * 512 + l];
      else       idx = span[b * 512 + l] * (1 - ip);
      sll  += lp[l][idx];
      sidx += (float)idx;
    }
    sll  = blockReduceSum(sll, red, t);
    sidx = blockReduceSum(sidx, red, t);
    if (t == 0) seq_ll[m] = (sidx > 0.f) ? sll : NEGV;
  }

  if (t == 0) {
    float mx = seq_ll[0];
#pragma unroll
    for (int m = 1; m < 9; ++m) mx = fmaxf(mx, seq_ll[m]);
    float sum = 0.f;
#pragma unroll
    for (int m = 0; m < 9; ++m) sum += expf(seq_ll[m] - mx);
    float lml = mx + logf(sum);
    out[b] = isbio[b] ? lml : NEGV;
  }
}

extern "C" void kernel_launch(void* const* d_in, const int* in_sizes, int n_in,
                              void* d_out, int out_size, void* d_ws, size_t ws_size,
                              hipStream_t stream) {
  const float* bert     = (const float*)d_in[0];
  const int*   seq_mask = (const int*)d_in[1];
  // d_in[2] wordpiece_mask: unused
  // d_in[3] answer_as_text_to_disjoint_bios: unused
  const int*   ans      = (const int*)d_in[4];
  const int*   span     = (const int*)d_in[5];
  const int*   isbio    = (const int*)d_in[6];
  const float* W1       = (const float*)d_in[7];
  const float* b1       = (const float*)d_in[8];
  const float* W2       = (const float*)d_in[9];
  const float* b2       = (const float*)d_in[10];
  float* out = (float*)d_out;

  char* ws = (char*)d_ws;
  float* partials     = (float*)ws;                                     // 768 KB, fully written
  unsigned short* Abf = (unsigned short*)(ws + (1 << 20));              // 32 MB
  unsigned short* W1T = (unsigned short*)(ws + (1 << 20) + (size_t)16384 * 1024 * 2); // 2 MB

  cvt_a<<<2048, 256, 0, stream>>>(bert, Abf, 16384 * 1024 / 8);
  cvt_w1t<<<1024, 256, 0, stream>>>(W1, W1T);
  gemm_fused<<<256, 512, 0, stream>>>(Abf, W1T, b1, W2, partials);
  finalize<<<32, 256, 0, stream>>>(partials, b2, seq_mask, ans, span, isbio, out);
}